// Round 2
// baseline (123.961 us; speedup 1.0000x reference)
//
#include <hip/hip_runtime.h>

// LogSparseAttention: B=2, L=2048, H=8, E=D=64, S=2048. fp32 in/out.
// Mask row r (from reference _row_mask with L==S==2048, log_l=11):
//   r < 22 : keys 0..r (full causal prefix)
//   r >= 22: keys {r-10 .. r} plus {r-10-2^i for i=0..10 if >= 0}
// <=22 active keys per row -> gather + online softmax, one wave per (b,h,l).
// Masked keys have score -1.25e8 -> exp == 0 exactly in fp32, so skipping
// them is numerically identical to the reference.

#define BB 2
#define LL 2048
#define HH 8
#define EE 64   // == wave size
#define SS 2048
#define DD 64

__global__ __launch_bounds__(256) void logsparse_attn_kernel(
    const float* __restrict__ Q,
    const float* __restrict__ K,
    const float* __restrict__ V,
    float* __restrict__ O)
{
    const int lane = threadIdx.x & 63;
    const int wave = threadIdx.x >> 6;
    const int row  = blockIdx.x * 4 + wave;        // global wave id = (b,h,l) row
    // consecutive waves -> consecutive l for K/V cache locality
    const int l  = row % LL;
    const int bh = row / LL;
    const int h  = bh % HH;
    const int b  = bh / HH;

    const float scale = 0.125f;  // 1/sqrt(64)

    // Q[b, l, h, lane] — contiguous 64 floats per wave (256B coalesced)
    const size_t qoff = (((size_t)b * LL + l) * HH + h) * (size_t)EE + lane;
    const float qv = Q[qoff];

    float m    = -1e30f;     // running max (wave-uniform value, replicated)
    float lsum = 0.0f;       // running denom
    float acc  = 0.0f;       // running numerator for dim d = lane

    auto process = [&](int s) {
        // K[b, s, h, lane] and V[b, s, h, lane] share the same flat offset (E == D)
        const size_t off = (((size_t)b * SS + s) * HH + h) * (size_t)EE + lane;
        const float kv = K[off];
        const float vv = V[off];
        float p = qv * kv;
        #pragma unroll
        for (int o = 32; o > 0; o >>= 1) p += __shfl_xor(p, o, 64);
        const float score = p * scale;           // full dot product, all lanes
        const float mn    = fmaxf(m, score);
        const float alpha = __expf(m - mn);      // first key: exp(-1e30-s) == 0
        const float w     = __expf(score - mn);
        lsum = lsum * alpha + w;
        acc  = acc  * alpha + w * vv;
        m    = mn;
    };

    if (l < 22) {
        for (int s = 0; s <= l; ++s) process(s);
    } else {
        const int base = l - 10;
        #pragma unroll
        for (int i = 10; i >= 0; --i) {
            const int p = base - (1 << i);
            if (p >= 0) process(p);             // wave-uniform branch
        }
        for (int s = base; s <= l; ++s) process(s);
    }

    O[qoff] = acc / lsum;
}

extern "C" void kernel_launch(void* const* d_in, const int* in_sizes, int n_in,
                              void* d_out, int out_size, void* d_ws, size_t ws_size,
                              hipStream_t stream) {
    const float* Q = (const float*)d_in[0];
    const float* K = (const float*)d_in[1];
    const float* V = (const float*)d_in[2];
    // d_in[3] = attention_mask (all-ones, unused by the reference math)
    float* O = (float*)d_out;

    const int rows   = BB * HH * LL;          // 32768 waves
    const int blocks = rows / 4;              // 4 waves per 256-thread block
    hipLaunchKernelGGL(logsparse_attn_kernel, dim3(blocks), dim3(256), 0, stream,
                       Q, K, V, O);
}

// Round 3
// 94.065 us; speedup vs baseline: 1.3178x; 1.3178x over previous
//
#include <hip/hip_runtime.h>

// LogSparseAttention: B=2, L=2048, H=8, E=D=64, S=2048. fp32 in/out.
// Mask row r (from reference _row_mask, L==S==2048, log_l=11):
//   r < 22 : keys 0..r (full causal prefix)
//   r >= 22: window {r-10..r} + taps {r-10-2^i, i=0..10, if >= 0}
// <=22 active keys/row. Wave = one (b,h,l) row, split into 4 groups x 16 lanes:
// group g handles key ordinal 4c+g of chunk c; lane (g,t) covers dims 4t..4t+3
// via float4. Dot reduce = 4 in-group shuffles; online softmax once per chunk
// with a wave-uniform chunk max (exact rescaling). Cross-group combine at end.

#define BB 2
#define LL 2048
#define HH 8
#define EE 64
#define SS 2048

__global__ __launch_bounds__(256) void logsparse_attn_kernel(
    const float* __restrict__ Q,
    const float* __restrict__ K,
    const float* __restrict__ V,
    float* __restrict__ O)
{
    const int lane = threadIdx.x & 63;
    const int wv   = threadIdx.x >> 6;
    const int row  = blockIdx.x * 4 + wv;   // consecutive waves -> consecutive l
    const int l  = row % LL;
    const int bh = row / LL;
    const int h  = bh % HH;
    const int b  = bh / HH;

    const int t = lane & 15;   // sub-lane within group: dims 4t..4t+3
    const int g = lane >> 4;   // key group 0..3

    const float scale = 0.125f;  // 1/sqrt(64)

    const size_t qbase = (((size_t)b * LL + l) * HH + h) * (size_t)EE;
    const float4 qf = *(const float4*)(Q + qbase + 4 * t);

    const float* Kb = K + ((size_t)b * SS * HH + (size_t)h) * 0 + ((size_t)b * SS * HH * EE + (size_t)h * EE);
    const float* Vb = V + ((size_t)b * SS * HH * EE + (size_t)h * EE);

    // active-key bookkeeping (wave-uniform)
    int ntaps, nkeys, w0;
    if (l < 22) { ntaps = 0; nkeys = l + 1; w0 = 0; }
    else {
        w0 = l - 10;
        ntaps = 32 - __clz(w0);          // floor(log2(w0)) + 1
        if (ntaps > 11) ntaps = 11;
        nkeys = ntaps + 11;              // taps + 11-wide window
    }
    const int nchunks = (nkeys + 3) >> 2;

    float  m  = -1e30f;                  // running max (wave-uniform)
    float  lw = 0.0f;                    // group-partial denom
    float4 acc = {0.f, 0.f, 0.f, 0.f};   // group-partial numerator, dims 4t..4t+3

    for (int c = 0; c < nchunks; ++c) {
        const int n      = 4 * c + g;
        const bool valid = (n < nkeys);
        const int nc     = valid ? n : (nkeys - 1);
        int key;
        if (l < 22)           key = nc;
        else if (nc < ntaps)  key = w0 - (1 << (ntaps - 1 - nc));  // log taps
        else                  key = w0 + (nc - ntaps);             // window
        const size_t off = ((size_t)key << 9) + 4 * t;   // key*H*E = key*512
        const float4 kf = *(const float4*)(Kb + off);
        const float4 vf = *(const float4*)(Vb + off);

        float p = qf.x * kf.x + qf.y * kf.y + qf.z * kf.z + qf.w * kf.w;
        p += __shfl_xor(p, 1, 64);
        p += __shfl_xor(p, 2, 64);
        p += __shfl_xor(p, 4, 64);
        p += __shfl_xor(p, 8, 64);       // score replicated within 16-lane group
        const float score = valid ? p * scale : -1e30f;

        float cm = score;                // wave-wide chunk max (2 shuffles)
        cm = fmaxf(cm, __shfl_xor(cm, 16, 64));
        cm = fmaxf(cm, __shfl_xor(cm, 32, 64));
        const float mn    = fmaxf(m, cm);
        const float alpha = __expf(m - mn);     // first chunk: exp(-1e30)=0
        const float wj    = __expf(score - mn); // invalid lanes: exp(-1e30)=0
        lw    = lw    * alpha + wj;
        acc.x = acc.x * alpha + wj * vf.x;
        acc.y = acc.y * alpha + wj * vf.y;
        acc.z = acc.z * alpha + wj * vf.z;
        acc.w = acc.w * alpha + wj * vf.w;
        m = mn;
    }

    // combine the 4 group-partials (same scaling history -> plain sums)
    lw    += __shfl_xor(lw, 16, 64);    lw    += __shfl_xor(lw, 32, 64);
    acc.x += __shfl_xor(acc.x, 16, 64); acc.x += __shfl_xor(acc.x, 32, 64);
    acc.y += __shfl_xor(acc.y, 16, 64); acc.y += __shfl_xor(acc.y, 32, 64);
    acc.z += __shfl_xor(acc.z, 16, 64); acc.z += __shfl_xor(acc.z, 32, 64);
    acc.w += __shfl_xor(acc.w, 16, 64); acc.w += __shfl_xor(acc.w, 32, 64);

    if (g == 0) {
        const float inv = 1.0f / lw;
        float4 o;
        o.x = acc.x * inv; o.y = acc.y * inv; o.z = acc.z * inv; o.w = acc.w * inv;
        *(float4*)(O + qbase + 4 * t) = o;
    }
}

extern "C" void kernel_launch(void* const* d_in, const int* in_sizes, int n_in,
                              void* d_out, int out_size, void* d_ws, size_t ws_size,
                              hipStream_t stream) {
    const float* Q = (const float*)d_in[0];
    const float* K = (const float*)d_in[1];
    const float* V = (const float*)d_in[2];
    // d_in[3] = attention_mask (all-ones, unused by the reference math)
    float* O = (float*)d_out;

    const int rows   = BB * HH * LL;   // 32768 waves
    const int blocks = rows / 4;       // 4 waves per 256-thread block
    hipLaunchKernelGGL(logsparse_attn_kernel, dim3(blocks), dim3(256), 0, stream,
                       Q, K, V, O);
}

// Round 4
// 92.505 us; speedup vs baseline: 1.3400x; 1.0169x over previous
//
#include <hip/hip_runtime.h>

// LogSparseAttention: B=2, L=2048, H=8, E=D=64, S=2048. fp32 in/out.
// Mask row r (from reference _row_mask, L==S==2048, log_l=11):
//   r < 22 : keys 0..r (full causal prefix)
//   r >= 22: window {r-10..r} + taps {r-10-2^i, i=0..10, if >= 0}
// <=22 active keys/row -> 6 chunks of 4 keys. Wave = one (b,h,l) row,
// 4 groups x 16 lanes; group g owns key ordinal 4c+g, lane (g,t) dims 4t..4t+3.
// Chain-free: 6 independent dot+DPP trees, per-group max (register-only),
// 6 independent exps, single epilogue rescale + cross-group combine.

#define BB 2
#define LL 2048
#define HH 8
#define EE 64
#define SS 2048

template<int CTRL>
__device__ __forceinline__ float dpp_add(float v) {
    int t = __builtin_amdgcn_mov_dpp(__float_as_int(v), CTRL, 0xF, 0xF, false);
    return v + __int_as_float(t);
}

__global__ __launch_bounds__(256) void logsparse_attn_kernel(
    const float* __restrict__ Q,
    const float* __restrict__ K,
    const float* __restrict__ V,
    float* __restrict__ O)
{
    const int lane = threadIdx.x & 63;
    const int wv   = threadIdx.x >> 6;
    const int row  = blockIdx.x * 4 + wv;   // consecutive waves -> consecutive l
    const int l  = row % LL;
    const int bh = row / LL;
    const int h  = bh & (HH - 1);
    const int b  = bh / HH;

    const int t = lane & 15;   // dims 4t..4t+3
    const int g = lane >> 4;   // key group 0..3

    const size_t qbase = (((size_t)b * LL + l) * HH + h) * (size_t)EE;
    const float4 qf = *(const float4*)(Q + qbase + 4 * t);

    const size_t bhoff = (size_t)b * ((size_t)SS * HH * EE) + (size_t)h * EE;
    const float* Kb = K + bhoff;
    const float* Vb = V + bhoff;

    // wave-uniform active-key bookkeeping
    int ntaps, nkeys, w0;
    if (l < 22) { ntaps = 0; nkeys = l + 1; w0 = 0; }
    else {
        w0 = l - 10;
        ntaps = 32 - __clz(w0);            // floor(log2(w0)) + 1
        if (ntaps > 11) ntaps = 11;
        nkeys = ntaps + 11;                // taps + 11-wide window
    }

    float  sc[6];
    float4 vv[6];
    #pragma unroll
    for (int c = 0; c < 6; ++c) {
        const int n  = 4 * c + g;
        const int nc = (n < nkeys) ? n : (nkeys - 1);   // clamp for safe load
        int key;
        if (l < 22)           key = nc;
        else if (nc < ntaps)  key = w0 - (1 << (ntaps - 1 - nc));  // log taps
        else                  key = w0 + (nc - ntaps);             // window
        const size_t off = ((size_t)key << 9) + 4 * t;  // key*H*E = key*512
        const float4 kf = *(const float4*)(Kb + off);
        vv[c] = *(const float4*)(Vb + off);

        float p = qf.x * kf.x + qf.y * kf.y + qf.z * kf.z + qf.w * kf.w;
        p = dpp_add<0xB1>(p);    // quad_perm(1,0,3,2)  xor1
        p = dpp_add<0x4E>(p);    // quad_perm(2,3,0,1)  xor2
        p = dpp_add<0x124>(p);   // row_ror:4
        p = dpp_add<0x128>(p);   // row_ror:8 -> sum replicated in 16-lane group
        sc[c] = (n < nkeys) ? p * 0.125f : -1e30f;
    }

    // per-group max (group-uniform, register-only)
    float mg = sc[0];
    #pragma unroll
    for (int c = 1; c < 6; ++c) mg = fmaxf(mg, sc[c]);

    // independent exps + weighted V accumulate
    float  lsum = 0.0f;
    float4 acc  = {0.f, 0.f, 0.f, 0.f};
    #pragma unroll
    for (int c = 0; c < 6; ++c) {
        const float w = __expf(sc[c] - mg);   // invalid: exp(-1e30-mg)=0
        lsum  += w;
        acc.x += w * vv[c].x;
        acc.y += w * vv[c].y;
        acc.z += w * vv[c].z;
        acc.w += w * vv[c].w;
    }

    // global max + rescale (fully-invalid group: exp(-1e30-M)=0 kills it)
    float M = mg;
    M = fmaxf(M, __shfl_xor(M, 16, 64));
    M = fmaxf(M, __shfl_xor(M, 32, 64));
    const float r = __expf(mg - M);
    lsum  *= r;
    acc.x *= r; acc.y *= r; acc.z *= r; acc.w *= r;

    // cross-group combine (plain sums after rescale)
    lsum  += __shfl_xor(lsum, 16, 64);    lsum  += __shfl_xor(lsum, 32, 64);
    acc.x += __shfl_xor(acc.x, 16, 64);   acc.x += __shfl_xor(acc.x, 32, 64);
    acc.y += __shfl_xor(acc.y, 16, 64);   acc.y += __shfl_xor(acc.y, 32, 64);
    acc.z += __shfl_xor(acc.z, 16, 64);   acc.z += __shfl_xor(acc.z, 32, 64);
    acc.w += __shfl_xor(acc.w, 16, 64);   acc.w += __shfl_xor(acc.w, 32, 64);

    if (g == 0) {
        const float inv = 1.0f / lsum;
        float4 o;
        o.x = acc.x * inv; o.y = acc.y * inv;
        o.z = acc.z * inv; o.w = acc.w * inv;
        *(float4*)(O + qbase + 4 * t) = o;
    }
}

extern "C" void kernel_launch(void* const* d_in, const int* in_sizes, int n_in,
                              void* d_out, int out_size, void* d_ws, size_t ws_size,
                              hipStream_t stream) {
    const float* Q = (const float*)d_in[0];
    const float* K = (const float*)d_in[1];
    const float* V = (const float*)d_in[2];
    // d_in[3] = attention_mask (all-ones, unused by the reference math)
    float* O = (float*)d_out;

    const int rows   = BB * HH * LL;   // 32768 waves
    const int blocks = rows / 4;       // 4 waves per 256-thread block
    hipLaunchKernelGGL(logsparse_attn_kernel, dim3(blocks), dim3(256), 0, stream,
                       Q, K, V, O);
}

// Round 5
// 91.239 us; speedup vs baseline: 1.3586x; 1.0139x over previous
//
#include <hip/hip_runtime.h>

// LogSparseAttention: B=2, L=2048, H=8, E=D=64, S=2048. fp32 in/out.
// Mask row r (from reference _row_mask, L==S==2048, log_l=11):
//   r < 22 : keys 0..r (full causal prefix)
//   r >= 22: window {r-10..r} + taps {r-10-2^i, i=0..10, if >= 0}
// <=22 active keys/row -> 6 chunks of 4 keys. Wave = one (b,h,l) row,
// 4 groups x 16 lanes; group g owns key ordinal 4c+g, lane (g,t) dims 4t..4t+3.
// Chain-free softmax (R4) + XCD-aware block swizzle (R5): blockIdx%8 selects
// the XCD, so logical = (blockIdx&7)*1024 + (blockIdx>>3) gives each XCD a
// contiguous run of 1024 blocks = 2 whole (b,h) pairs -> K/V/Q working set
// ~3 MB fits the 4 MB per-XCD L2; key loads become L2 hits instead of L3.

#define BB 2
#define LL 2048
#define HH 8
#define EE 64
#define SS 2048

template<int CTRL>
__device__ __forceinline__ float dpp_add(float v) {
    int t = __builtin_amdgcn_mov_dpp(__float_as_int(v), CTRL, 0xF, 0xF, false);
    return v + __int_as_float(t);
}

__global__ __launch_bounds__(256) void logsparse_attn_kernel(
    const float* __restrict__ Q,
    const float* __restrict__ K,
    const float* __restrict__ V,
    float* __restrict__ O)
{
    const int lane = threadIdx.x & 63;
    const int wv   = threadIdx.x >> 6;
    // XCD-aware swizzle: 8192 blocks, launch block b -> XCD b%8 (round robin).
    // logical id gives XCD x the contiguous range [x*1024, (x+1)*1024).
    const int lb  = ((blockIdx.x & 7) << 10) | (blockIdx.x >> 3);
    const int row = lb * 4 + wv;            // consecutive waves -> consecutive l
    const int l  = row % LL;
    const int bh = row / LL;
    const int h  = bh & (HH - 1);
    const int b  = bh / HH;

    const int t = lane & 15;   // dims 4t..4t+3
    const int g = lane >> 4;   // key group 0..3

    const size_t qbase = (((size_t)b * LL + l) * HH + h) * (size_t)EE;
    const float4 qf = *(const float4*)(Q + qbase + 4 * t);

    const size_t bhoff = (size_t)b * ((size_t)SS * HH * EE) + (size_t)h * EE;
    const float* Kb = K + bhoff;
    const float* Vb = V + bhoff;

    // wave-uniform active-key bookkeeping
    int ntaps, nkeys, w0;
    if (l < 22) { ntaps = 0; nkeys = l + 1; w0 = 0; }
    else {
        w0 = l - 10;
        ntaps = 32 - __clz(w0);            // floor(log2(w0)) + 1
        if (ntaps > 11) ntaps = 11;
        nkeys = ntaps + 11;                // taps + 11-wide window
    }

    float  sc[6];
    float4 vv[6];
    #pragma unroll
    for (int c = 0; c < 6; ++c) {
        const int n  = 4 * c + g;
        const int nc = (n < nkeys) ? n : (nkeys - 1);   // clamp for safe load
        int key;
        if (l < 22)           key = nc;
        else if (nc < ntaps)  key = w0 - (1 << (ntaps - 1 - nc));  // log taps
        else                  key = w0 + (nc - ntaps);             // window
        const size_t off = ((size_t)key << 9) + 4 * t;  // key*H*E = key*512
        const float4 kf = *(const float4*)(Kb + off);
        vv[c] = *(const float4*)(Vb + off);

        float p = qf.x * kf.x + qf.y * kf.y + qf.z * kf.z + qf.w * kf.w;
        p = dpp_add<0xB1>(p);    // quad_perm(1,0,3,2)  xor1
        p = dpp_add<0x4E>(p);    // quad_perm(2,3,0,1)  xor2
        p = dpp_add<0x124>(p);   // row_ror:4
        p = dpp_add<0x128>(p);   // row_ror:8 -> sum replicated in 16-lane group
        sc[c] = (n < nkeys) ? p * 0.125f : -1e30f;
    }

    // per-group max (group-uniform, register-only)
    float mg = sc[0];
    #pragma unroll
    for (int c = 1; c < 6; ++c) mg = fmaxf(mg, sc[c]);

    // independent exps + weighted V accumulate
    float  lsum = 0.0f;
    float4 acc  = {0.f, 0.f, 0.f, 0.f};
    #pragma unroll
    for (int c = 0; c < 6; ++c) {
        const float w = __expf(sc[c] - mg);   // invalid: exp(-1e30-mg)=0
        lsum  += w;
        acc.x += w * vv[c].x;
        acc.y += w * vv[c].y;
        acc.z += w * vv[c].z;
        acc.w += w * vv[c].w;
    }

    // global max + rescale (fully-invalid group: exp(-1e30-M)=0 kills it)
    float M = mg;
    M = fmaxf(M, __shfl_xor(M, 16, 64));
    M = fmaxf(M, __shfl_xor(M, 32, 64));
    const float r = __expf(mg - M);
    lsum  *= r;
    acc.x *= r; acc.y *= r; acc.z *= r; acc.w *= r;

    // cross-group combine (plain sums after rescale)
    lsum  += __shfl_xor(lsum, 16, 64);    lsum  += __shfl_xor(lsum, 32, 64);
    acc.x += __shfl_xor(acc.x, 16, 64);   acc.x += __shfl_xor(acc.x, 32, 64);
    acc.y += __shfl_xor(acc.y, 16, 64);   acc.y += __shfl_xor(acc.y, 32, 64);
    acc.z += __shfl_xor(acc.z, 16, 64);   acc.z += __shfl_xor(acc.z, 32, 64);
    acc.w += __shfl_xor(acc.w, 16, 64);   acc.w += __shfl_xor(acc.w, 32, 64);

    if (g == 0) {
        const float inv = 1.0f / lsum;
        float4 o;
        o.x = acc.x * inv; o.y = acc.y * inv;
        o.z = acc.z * inv; o.w = acc.w * inv;
        *(float4*)(O + qbase + 4 * t) = o;
    }
}

extern "C" void kernel_launch(void* const* d_in, const int* in_sizes, int n_in,
                              void* d_out, int out_size, void* d_ws, size_t ws_size,
                              hipStream_t stream) {
    const float* Q = (const float*)d_in[0];
    const float* K = (const float*)d_in[1];
    const float* V = (const float*)d_in[2];
    // d_in[3] = attention_mask (all-ones, unused by the reference math)
    float* O = (float*)d_out;

    const int rows   = BB * HH * LL;   // 32768 waves
    const int blocks = rows / 4;       // 8192 blocks, 4 waves each
    hipLaunchKernelGGL(logsparse_attn_kernel, dim3(blocks), dim3(256), 0, stream,
                       Q, K, V, O);
}